// Round 10
// baseline (271.379 us; speedup 1.0000x reference)
//
#include <hip/hip_runtime.h>
#include <stdint.h>

typedef unsigned short u16;
typedef __bf16 bf16x8 __attribute__((ext_vector_type(8)));
typedef float f32x4 __attribute__((ext_vector_type(4)));
typedef __attribute__((address_space(1))) void gvoid;
typedef __attribute__((address_space(3))) void lvoid;

#define NTOK 32768

__device__ __forceinline__ u16 f2bf(float f) {
    unsigned u = __float_as_uint(f);
    u += 0x7fffu + ((u >> 16) & 1u);
    return (u16)(u >> 16);
}
__device__ __forceinline__ float softplusf(float x) {
    return fmaxf(x, 0.f) + log1pf(expf(-fabsf(x)));
}
__device__ __forceinline__ float geluf(float x) {
    return 0.5f * x * (1.f + erff(x * 0.7071067811865475f));
}
__device__ __forceinline__ float wave_sum(float v) {
#pragma unroll
    for (int o = 32; o > 0; o >>= 1) v += __shfl_xor(v, o);
    return v;
}
__device__ __forceinline__ float blk_sum(float v) {
    __shared__ float sm[4];
    v = wave_sum(v);
    __syncthreads();
    if ((threadIdx.x & 63) == 0) sm[threadIdx.x >> 6] = v;
    __syncthreads();
    return sm[0] + sm[1] + sm[2] + sm[3];
}

// ---------------------------------------------------------------- fold / precompute
// Astk rows: [0,512) vn folded, [512,1024) un folded, [1024,1032) bank-proj folded, [1032,1152) zero
__global__ void k_fold(
    const float* __restrict__ vnw1, const float* __restrict__ vnnw, const float* __restrict__ vnnb, const float* __restrict__ vnb1,
    const float* __restrict__ unw1, const float* __restrict__ unnw, const float* __restrict__ unnb, const float* __restrict__ unb1,
    const float* __restrict__ sbpw, const float* __restrict__ sbpb, const float* __restrict__ sbnw, const float* __restrict__ sbnb,
    const float* __restrict__ cbpw, const float* __restrict__ cbpb, const float* __restrict__ cbnw, const float* __restrict__ cbnb,
    const float* __restrict__ outw, const float* __restrict__ enw, const float* __restrict__ enb,
    const float* __restrict__ prw, const float* __restrict__ prb,
    const float* __restrict__ rsw, const float* __restrict__ rsb,
    const float* __restrict__ sspw, const float* __restrict__ sspb,
    const float* __restrict__ cspw, const float* __restrict__ cspb,
    const float* __restrict__ vnw2, const float* __restrict__ vnb2,
    u16* __restrict__ Astk, float* __restrict__ bstk, float* __restrict__ pb,
    u16* __restrict__ Aow, u16* __restrict__ vnT,
    float* __restrict__ a_en, float* __restrict__ a_pr, float* __restrict__ a_rs,
    float* __restrict__ b_vo, float* __restrict__ c_cn, float* __restrict__ Mss, float* __restrict__ Mcs)
{
    const int b = blockIdx.x, t = threadIdx.x;
    if (b < 1024) {
        const float *w1, *nw, *nb; float bias;
        if (b < 512) { w1 = vnw1 + (size_t)b * 512; nw = vnnw; nb = vnnb; bias = vnb1[b]; }
        else { int r = b - 512; w1 = unw1 + (size_t)r * 512; nw = unnw; nb = unnb; bias = unb1[r]; }
        float part = 0.f;
        for (int d = t; d < 512; d += 256) {
            float wv = w1[d];
            Astk[(size_t)b * 512 + d] = f2bf(wv * nw[d]);
            part += wv * nb[d];
        }
        float s = blk_sum(part);
        if (t == 0) bstk[b] = bias + s;
    } else if (b < 1032) {
        int j = b - 1024;
        const float *pw, *nw, *nb; float bias;
        if (j < 4) { pw = sbpw + j * 512; nw = sbnw; nb = sbnb; bias = sbpb[j]; }
        else { pw = cbpw + (j - 4) * 512; nw = cbnw; nb = cbnb; bias = cbpb[j - 4]; }
        float part = 0.f;
        for (int d = t; d < 512; d += 256) {
            float wv = pw[d];
            Astk[(size_t)(1024 + j) * 512 + d] = f2bf(wv * nw[d]);
            part += wv * nb[d];
        }
        float s = blk_sum(part);
        if (t == 0) pb[j] = bias + s;
    } else if (b < 1152) {
        for (int d = t; d < 512; d += 256) Astk[(size_t)b * 512 + d] = 0;
    } else if (b < 1664) {
        int i = b - 1152;
        const float* ow = outw + (size_t)i * 3072;
        float pen = 0, ppr = 0, prs = 0, pbv = 0, pcc = 0;
        float pms[8], pmc[8];
#pragma unroll
        for (int k = 0; k < 8; k++) { pms[k] = 0.f; pmc[k] = 0.f; }
        for (int h = t; h < 512; h += 256) {
            float o0 = ow[h];        Aow[(size_t)i * 512 + h] = f2bf(o0); pbv += o0 * vnb2[h];
            float o1 = ow[512 + h];  pen += o1 * enw[h]; pcc += o1 * enb[h];
            float o2 = ow[1024 + h]; ppr += o2 * prw[h]; pcc += o2 * prb[h];
            float o3 = ow[1536 + h]; prs += o3 * rsw[h]; pcc += o3 * rsb[h];
            float o4 = ow[2048 + h]; pcc += o4 * sspb[h];
            float o5 = ow[2560 + h]; pcc += o5 * cspb[h];
#pragma unroll
            for (int k = 0; k < 8; k++) { pms[k] += o4 * sspw[h * 8 + k]; pmc[k] += o5 * cspw[h * 8 + k]; }
        }
        float r;
        r = blk_sum(pen); if (t == 0) a_en[i] = r;
        r = blk_sum(ppr); if (t == 0) a_pr[i] = r;
        r = blk_sum(prs); if (t == 0) a_rs[i] = r;
        r = blk_sum(pbv); if (t == 0) b_vo[i] = r;
        r = blk_sum(pcc); if (t == 0) c_cn[i] = r;
        for (int k = 0; k < 8; k++) { r = blk_sum(pms[k]); if (t == 0) Mss[i * 8 + k] = r; }
        for (int k = 0; k < 8; k++) { r = blk_sum(pmc[k]); if (t == 0) Mcs[i * 8 + k] = r; }
    } else {
        int hrow = b - 1664;
        for (int o = t; o < 512; o += 256)
            vnT[(size_t)hrow * 512 + o] = f2bf(vnw2[(size_t)o * 512 + hrow]);
    }
}

// ================================================================ A-in-registers 128x128 GEMM mainloop, 256 threads
// Invariant-breaker vs R4/R9 (both 70 µs, MfmaUtil 21%): A-fragments load straight from
// global (L2/L3-resident) into VGPRs — MFMA A-operand never touches LDS. Halves LDS-pipe
// reads per K-tile (16 -> 8 b128/wave) and the per-wave A-loads are issued one K-tile ahead
// (latency hidden under compute). B keeps global_load_lds + both-sides XOR swizzle.
// 4 waves: wr=(w>>1)*64, wc=(w&1)*64; acc[4][4]=64 VGPR; a0/a1 dbuf = 64 VGPR.
// LDS 36KB: lB0/lB1 [128][64] u16 + epilogue scratch overlay.
__device__ __forceinline__ void stg_b(const u16* __restrict__ Bg, size_t brow0, int tile,
                                      u16* lbase, int w, int l)
{
    const int kt = tile * 64;
    const int rchunk = l >> 3;
    const int gc = (((l & 7) ^ ((l >> 3) & 7)) << 3);   // pre-swizzled source col (u16)
#pragma unroll
    for (int i = 0; i < 4; i++) {
        const int r0 = (w * 4 + i) * 8;
        __builtin_amdgcn_global_load_lds(
            (gvoid*)const_cast<u16*>(Bg + (brow0 + r0 + rchunk) * 512 + kt + gc),
            (lvoid*)(lbase + r0 * 64), 16, 0, 0);
    }
}

__device__ __forceinline__ void lda(const u16* __restrict__ Ag, size_t arow0, int tile,
                                    bf16x8 (&ar)[4][2], int wr, int l)
{
    const int kt = tile * 64;
    const int fkb = (l >> 4) << 3;
#pragma unroll
    for (int rt = 0; rt < 4; rt++)
#pragma unroll
        for (int ks = 0; ks < 2; ks++)
            ar[rt][ks] = *(const bf16x8*)(Ag + (arow0 + wr + rt * 16 + (l & 15)) * 512 + kt + ks * 32 + fkb);
}

__device__ __forceinline__ void gcomp(const u16* lB, bf16x8 (&aw)[4][2], f32x4 (&acc)[4][4],
                                      int wc, int l)
{
#pragma unroll
    for (int ks = 0; ks < 2; ks++) {
        bf16x8 bf[4];
#pragma unroll
        for (int ct = 0; ct < 4; ct++) {
            const int row = wc + ct * 16 + (l & 15);
            const int s = (ks * 4 + (l >> 4)) ^ (row & 7);
            bf[ct] = *(const bf16x8*)(lB + row * 64 + (s << 3));
        }
#pragma unroll
        for (int rt = 0; rt < 4; rt++)
#pragma unroll
            for (int ct = 0; ct < 4; ct++)
                acc[rt][ct] = __builtin_amdgcn_mfma_f32_16x16x32_bf16(aw[rt][ks], bf[ct], acc[rt][ct], 0, 0, 0);
    }
}

// K = 512 (8 K-tiles of BK=64)
__device__ __forceinline__ void gemm_areg(const u16* __restrict__ Ag, const u16* __restrict__ Bg,
                                          size_t arow0, size_t brow0,
                                          u16* sm, f32x4 (&acc)[4][4], int w, int l)
{
    const int wr = ((w >> 1) << 6), wc = ((w & 1) << 6);
    u16* const lB0 = sm;
    u16* const lB1 = sm + 8192;
    bf16x8 a0[4][2], a1[4][2];

    stg_b(Bg, brow0, 0, lB0, w, l);
    lda(Ag, arow0, 0, a0, wr, l);
    __syncthreads();
#pragma unroll
    for (int tp = 0; tp < 4; ++tp) {
        const int t1 = 2 * tp + 1, t2 = 2 * tp + 2;
        // even tile from (lB0, a0); prefetch t1
        stg_b(Bg, brow0, t1, lB1, w, l);
        lda(Ag, arow0, t1, a1, wr, l);
        gcomp(lB0, a0, acc, wc, l);
        __syncthreads();
        // odd tile from (lB1, a1); prefetch t2
        if (t2 < 8) {
            stg_b(Bg, brow0, t2, lB0, w, l);
            lda(Ag, arow0, t2, a0, wr, l);
        }
        gcomp(lB1, a1, acc, wc, l);
        __syncthreads();
    }
}

// ---------------------------------------------------------------- per-token standardize (memory-bound)
__global__ void k_token(const float* __restrict__ x, u16* __restrict__ Ybf)
{
    const int w = threadIdx.x >> 6, l = threadIdx.x & 63;
    const int n = blockIdx.x * 4 + w;
    const float* xr = x + (size_t)n * 512;
    float4 xa = *(const float4*)(xr + 4 * l);
    float4 xb = *(const float4*)(xr + 256 + 4 * l);
    float v[8] = {xa.x, xa.y, xa.z, xa.w, xb.x, xb.y, xb.z, xb.w};
    float s1 = 0.f, s2 = 0.f;
#pragma unroll
    for (int c = 0; c < 8; c++) { s1 += v[c]; s2 += v[c] * v[c]; }
    s1 = wave_sum(s1); s2 = wave_sum(s2);
    const float mean = s1 * (1.f / 512.f);
    const float var = s2 * (1.f / 512.f) - mean * mean;
    const float rstd = rsqrtf(var + 1e-5f);
    float y[8];
#pragma unroll
    for (int c = 0; c < 8; c++) y[c] = (v[c] - mean) * rstd;
    *(ushort4*)(Ybf + (size_t)n * 512 + 4 * l) = make_ushort4(f2bf(y[0]), f2bf(y[1]), f2bf(y[2]), f2bf(y[3]));
    *(ushort4*)(Ybf + (size_t)n * 512 + 256 + 4 * l) = make_ushort4(f2bf(y[4]), f2bf(y[5]), f2bf(y[6]), f2bf(y[7]));
}

// ---------------------------------------------------------------- GEMM1: bx 0-3 H, 4-7 un dot, 8 bank proj, 9 Wvo tiles
__global__ __launch_bounds__(256) void k_gemm1(const u16* __restrict__ Y, const u16* __restrict__ Ast,
                                               const float* __restrict__ bstk, const float* __restrict__ pb,
                                               const float* __restrict__ unw2,
                                               const u16* __restrict__ Aow, const u16* __restrict__ vnT,
                                               u16* __restrict__ Wvo,
                                               u16* __restrict__ H, float* __restrict__ wp,
                                               float* __restrict__ wdotp)
{
    __shared__ __align__(16) u16 smem[18432];   // 36 KB: lB dbuf 32KB; epilogue overlays full extent
    const f32x4 zero = {0.f, 0.f, 0.f, 0.f};
    f32x4 acc[4][4];
#pragma unroll
    for (int a = 0; a < 4; a++)
#pragma unroll
        for (int c = 0; c < 4; c++) acc[a][c] = zero;
    // XCD-aware bijective swizzle (nwg = 10*256 = 2560, %8==0)
    const int nwg = gridDim.x * gridDim.y;
    const int lin = blockIdx.y * gridDim.x + blockIdx.x;
    const int swz = (lin & 7) * (nwg >> 3) + (lin >> 3);
    const int by = swz / gridDim.x, bx = swz % gridDim.x;
    const int t = threadIdx.x, w = t >> 6, l = t & 63;
    const int wr = ((w >> 1) << 6), wc = ((w & 1) << 6);
    const int lr = ((l >> 4) << 2), lc = l & 15;

    if (bx == 9) {
        // fold the 512x512 Wvo = Aow @ vnT^T GEMM into this grid (16 tiles); rest exit
        if (by >= 16) return;
        const size_t ar = (size_t)(by >> 2) * 128, br = (size_t)(by & 3) * 128;
        gemm_areg(Aow, vnT, ar, br, smem, acc, w, l);
        const int rbase = (by >> 2) * 128 + wr;
        const int cbase = (by & 3) * 128 + wc;
#pragma unroll
        for (int rt = 0; rt < 4; rt++)
#pragma unroll
            for (int ct = 0; ct < 4; ct++)
#pragma unroll
                for (int j = 0; j < 4; j++)
                    Wvo[(size_t)(rbase + rt * 16 + lr + j) * 512 + cbase + ct * 16 + lc] = f2bf(acc[rt][ct][j]);
        return;
    }

    gemm_areg(Y, Ast, (size_t)by * 128, (size_t)bx * 128, smem, acc, w, l);

    if (bx == 8) {
        // bank projections: only cols 1024..1031 real ((w&1)==0, ct=0, lc<8)
        if ((w & 1) == 0 && lc < 8) {
            const float bv = pb[lc];
            const int rbase = by * 128 + wr;
#pragma unroll
            for (int rt = 0; rt < 4; rt++)
#pragma unroll
                for (int j = 0; j < 4; j++) {
                    const int n = rbase + rt * 16 + lr + j;
                    wp[(size_t)n * 8 + lc] = acc[rt][0][j] + bv;
                }
        }
        return;
    }
    if (bx >= 4) {
        // uncertainty half: dot( gelu(u_h), un_w2 ) partials; H never materialized
        const int cb = (bx - 4) * 128;
        float part[4][4];
#pragma unroll
        for (int rt = 0; rt < 4; rt++)
#pragma unroll
            for (int j = 0; j < 4; j++) part[rt][j] = 0.f;
#pragma unroll
        for (int ct = 0; ct < 4; ct++) {
            const int col = cb + wc + ct * 16 + lc;
            const float bv = bstk[512 + col];
            const float w2 = unw2[col];
#pragma unroll
            for (int rt = 0; rt < 4; rt++)
#pragma unroll
                for (int j = 0; j < 4; j++)
                    part[rt][j] += geluf(acc[rt][ct][j] + bv) * w2;
        }
        float* sf = (float*)smem;   // 128 rows x 32 slots = 16 KB
        const int slot = ((w & 1) << 4) | lc;
        __syncthreads();
#pragma unroll
        for (int rt = 0; rt < 4; rt++)
#pragma unroll
            for (int j = 0; j < 4; j++)
                sf[(wr + rt * 16 + lr + j) * 32 + slot] = part[rt][j];
        __syncthreads();
        if (t < 128) {
            float s = 0.f;
#pragma unroll
            for (int k2 = 0; k2 < 32; k2++) s += sf[t * 32 + k2];
            wdotp[(size_t)(bx - 4) * NTOK + by * 128 + t] = s;
        }
        return;
    }
    // v-half: gelu + bias, stage C-tile in LDS [128][136] u16 (34 KB), coalesced row writes
    __syncthreads();
#pragma unroll
    for (int ct = 0; ct < 4; ct++) {
        const int col = wc + ct * 16 + lc;
        const float bv = bstk[bx * 128 + col];
#pragma unroll
        for (int rt = 0; rt < 4; rt++) {
            const int row = wr + rt * 16 + lr;
#pragma unroll
            for (int j = 0; j < 4; j++)
                smem[(row + j) * 136 + col] = f2bf(geluf(acc[rt][ct][j] + bv));
        }
    }
    __syncthreads();
    const size_t gbase = (size_t)(by * 128) * 512 + bx * 128;
#pragma unroll
    for (int jj = 0; jj < 8; jj++) {
        const int r = jj * 16 + (t >> 4), u = t & 15;
        bf16x8 vv = *(const bf16x8*)(smem + r * 136 + u * 8);
        *(bf16x8*)(H + gbase + (size_t)r * 512 + u * 8) = vv;
    }
}

// ---------------------------------------------------------------- per-token scalar math (1 thread = 1 token)
__global__ void k_bank(const float* __restrict__ wp, const float* __restrict__ wdotp,
                       const float* __restrict__ unb2,
                       const float* __restrict__ sbsw, const float* __restrict__ sbsb,
                       const float* __restrict__ cbsw, const float* __restrict__ cbsb,
                       const float* __restrict__ suplog, const float* __restrict__ confw,
                       const float* __restrict__ drvb, const float* __restrict__ biasres,
                       const float* __restrict__ emlg, const float* __restrict__ emll,
                       const float* __restrict__ emlb, const float* __restrict__ updthr,
                       float* __restrict__ wss, float* __restrict__ wcs, float* __restrict__ wsc)
{
    const int n = blockIdx.x * 256 + threadIdx.x;
    float4 p0 = *(const float4*)(wp + (size_t)n * 8);
    float4 p1 = *(const float4*)(wp + (size_t)n * 8 + 4);
    float p[8] = {p0.x, p0.y, p0.z, p0.w, p1.x, p1.y, p1.z, p1.w};
    const float dot = wdotp[n] + wdotp[NTOK + n] + wdotp[2 * NTOK + n] + wdotp[3 * NTOK + n];
    float sf[4], lsv[4], cf[4];
#pragma unroll
    for (int j = 0; j < 4; j++) {
        sf[j] = softplusf(p[j]) + 1e-4f;
        lsv[j] = logf(sf[j]);
        cf[j] = softplusf(p[j + 4]);
    }
    const float smn = 0.25f * (sf[0] + sf[1] + sf[2] + sf[3]);
    float sd = 0.f;
#pragma unroll
    for (int j = 0; j < 4; j++) sd += (sf[j] - smn) * (sf[j] - smn);
    const float sstd = sqrtf(0.25f * sd);
    const float lmn = 0.25f * (lsv[0] + lsv[1] + lsv[2] + lsv[3]);
    const float lmx = fmaxf(fmaxf(lsv[0], lsv[1]), fmaxf(lsv[2], lsv[3]));
    const float cmn = 0.25f * (cf[0] + cf[1] + cf[2] + cf[3]);
    float cd = 0.f;
#pragma unroll
    for (int j = 0; j < 4; j++) cd += (cf[j] - cmn) * (cf[j] - cmn);
    const float cstd = sqrtf(0.25f * cd);
    const float cmx = fmaxf(fmaxf(cf[0], cf[1]), fmaxf(cf[2], cf[3]));
    const float cmi = fminf(fminf(cf[0], cf[1]), fminf(cf[2], cf[3]));
    float seed_s[4] = {smn, sstd, lmn, lmx};
    float seed_c[4] = {cmn, cstd, cmx, cmi};
    float a4[8], b4[8];
#pragma unroll
    for (int k = 0; k < 8; k++) {
        float a = sbsb[k], b2 = cbsb[k];
#pragma unroll
        for (int j = 0; j < 4; j++) { a += sbsw[k * 4 + j] * seed_s[j]; b2 += cbsw[k * 4 + j] * seed_c[j]; }
        a4[k] = a; b4[k] = b2;
    }
    *(float4*)(wss + (size_t)n * 8)     = make_float4(a4[0], a4[1], a4[2], a4[3]);
    *(float4*)(wss + (size_t)n * 8 + 4) = make_float4(a4[4], a4[5], a4[6], a4[7]);
    *(float4*)(wcs + (size_t)n * 8)     = make_float4(b4[0], b4[1], b4[2], b4[3]);
    *(float4*)(wcs + (size_t)n * 8 + 4) = make_float4(b4[4], b4[5], b4[6], b4[7]);
    float mx = fmaxf(fmaxf(suplog[0], suplog[1]), fmaxf(suplog[2], suplog[3]));
    float e[4], se = 0.f;
#pragma unroll
    for (int j = 0; j < 4; j++) { e[j] = expf(suplog[j] - mx); se += e[j]; }
    float dv = 0.f, wcv = 0.f;
#pragma unroll
    for (int j = 0; j < 4; j++) { dv += lsv[j] * (e[j] / se); wcv += cf[j] * softplusf(confw[j]); }
    const float drive = drvb[0] + 0.5f * dv;
    const float unc = softplusf(dot + unb2[0]);
    const float res = biasres[0] + 0.5f * wcv + unc;
    const float er = emlg[0] * drive - emll[0] * res + emlb[0];
    const float energy = 3.f * tanhf(er * (1.f / 3.f));
    const float act = 1.f / (1.f + expf(-energy));
    const float prc = softplusf(energy - updthr[0]);
    wsc[(size_t)n * 4 + 0] = act;
    wsc[(size_t)n * 4 + 1] = energy;
    wsc[(size_t)n * 4 + 2] = prc;
    wsc[(size_t)n * 4 + 3] = res;
}

// ---------------------------------------------------------------- GEMM2: value path + fused MERC epilogue
__global__ __launch_bounds__(256) void k_gemm2(const u16* __restrict__ H, const u16* __restrict__ Wvo,
    const float* __restrict__ wsc, const float* __restrict__ wss, const float* __restrict__ wcs,
    const float* __restrict__ a_en, const float* __restrict__ a_pr, const float* __restrict__ a_rs,
    const float* __restrict__ b_vo, const float* __restrict__ c_cn,
    const float* __restrict__ Mss, const float* __restrict__ Mcs,
    const float* __restrict__ outb, float* __restrict__ out)
{
    __shared__ __align__(16) u16 smem[16384];
    const f32x4 zero = {0.f, 0.f, 0.f, 0.f};
    f32x4 acc[4][4];
#pragma unroll
    for (int a = 0; a < 4; a++)
#pragma unroll
        for (int c = 0; c < 4; c++) acc[a][c] = zero;
    // XCD-aware bijective swizzle (nwg = 4*256 = 1024, %8==0)
    const int nwg = gridDim.x * gridDim.y;
    const int lin = blockIdx.y * gridDim.x + blockIdx.x;
    const int swz = (lin & 7) * (nwg >> 3) + (lin >> 3);
    const int by = swz / gridDim.x, bx = swz % gridDim.x;
    const int t = threadIdx.x, w = t >> 6, l = t & 63;

    gemm_areg(H, Wvo, (size_t)by * 128, (size_t)bx * 128, smem, acc, w, l);

    const int rbase = by * 128 + ((w >> 1) << 6);
    const int cbase = bx * 128 + ((w & 1) << 6);
    const int lr = ((l >> 4) << 2), lc = l & 15;
    float bvo4[4], aen4[4], apr4[4], ars4[4], cc4[4], ms4[4][8], mc4[4][8];
#pragma unroll
    for (int ct = 0; ct < 4; ct++) {
        const int i = cbase + ct * 16 + lc;
        bvo4[ct] = b_vo[i]; aen4[ct] = a_en[i]; apr4[ct] = a_pr[i]; ars4[ct] = a_rs[i];
        cc4[ct] = c_cn[i] + outb[i];
#pragma unroll
        for (int k = 0; k < 8; k++) { ms4[ct][k] = Mss[i * 8 + k]; mc4[ct][k] = Mcs[i * 8 + k]; }
    }
#pragma unroll
    for (int rt = 0; rt < 4; rt++)
#pragma unroll
        for (int j = 0; j < 4; j++) {
            const int n = rbase + rt * 16 + lr + j;
            const float act = wsc[(size_t)n * 4 + 0];
            const float eng = wsc[(size_t)n * 4 + 1];
            const float prc = wsc[(size_t)n * 4 + 2];
            const float res = wsc[(size_t)n * 4 + 3];
            float sv[8], cv[8];
#pragma unroll
            for (int k = 0; k < 8; k++) { sv[k] = wss[(size_t)n * 8 + k]; cv[k] = wcs[(size_t)n * 8 + k]; }
#pragma unroll
            for (int ct = 0; ct < 4; ct++) {
                const int i = cbase + ct * 16 + lc;
                float o = act * (acc[rt][ct][j] + bvo4[ct]) + eng * aen4[ct] + prc * apr4[ct]
                        + res * ars4[ct] + cc4[ct];
#pragma unroll
                for (int k = 0; k < 8; k++) o += ms4[ct][k] * sv[k] + mc4[ct][k] * cv[k];
                out[(size_t)n * 512 + i] = o;
            }
        }
}

// ---------------------------------------------------------------- host
extern "C" void kernel_launch(void* const* d_in, const int* in_sizes, int n_in,
                              void* d_out, int out_size, void* d_ws, size_t ws_size,
                              hipStream_t stream)
{
    const float* x       = (const float*)d_in[0];
    const float* sbnw    = (const float*)d_in[1];
    const float* sbnb    = (const float*)d_in[2];
    const float* sbpw    = (const float*)d_in[3];
    const float* sbpb    = (const float*)d_in[4];
    const float* sbsw    = (const float*)d_in[5];
    const float* sbsb    = (const float*)d_in[6];
    const float* cbnw    = (const float*)d_in[7];
    const float* cbnb    = (const float*)d_in[8];
    const float* cbpw    = (const float*)d_in[9];
    const float* cbpb    = (const float*)d_in[10];
    const float* cbsw    = (const float*)d_in[11];
    const float* cbsb    = (const float*)d_in[12];
    const float* vnnw    = (const float*)d_in[13];
    const float* vnnb    = (const float*)d_in[14];
    const float* vnw1    = (const float*)d_in[15];
    const float* vnb1    = (const float*)d_in[16];
    const float* vnw2    = (const float*)d_in[17];
    const float* vnb2    = (const float*)d_in[18];
    const float* unnw    = (const float*)d_in[19];
    const float* unnb    = (const float*)d_in[20];
    const float* unw1    = (const float*)d_in[21];
    const float* unb1    = (const float*)d_in[22];
    const float* unw2    = (const float*)d_in[23];
    const float* unb2    = (const float*)d_in[24];
    const float* enw     = (const float*)d_in[25];
    const float* enb     = (const float*)d_in[26];
    const float* prw     = (const float*)d_in[27];
    const float* prb     = (const float*)d_in[28];
    const float* rsw     = (const float*)d_in[29];
    const float* rsb     = (const float*)d_in[30];
    const float* sspw    = (const float*)d_in[31];
    const float* sspb    = (const float*)d_in[32];
    const float* cspw    = (const float*)d_in[33];
    const float* cspb    = (const float*)d_in[34];
    const float* outw    = (const float*)d_in[35];
    const float* outb    = (const float*)d_in[36];
    const float* suplog  = (const float*)d_in[37];
    const float* confw   = (const float*)d_in[38];
    const float* drvb    = (const float*)d_in[39];
    const float* biasres = (const float*)d_in[40];
    const float* updthr  = (const float*)d_in[41];
    const float* emlg    = (const float*)d_in[42];
    const float* emll    = (const float*)d_in[43];
    const float* emlb    = (const float*)d_in[44];
    float* out = (float*)d_out;
    (void)in_sizes; (void)n_in; (void)out_size; (void)ws_size;

    char* wsp = (char*)d_ws;
    size_t off = 0;
    auto alloc = [&](size_t bytes) { char* p = wsp + off; off = (off + bytes + 255) & ~(size_t)255; return p; };
    u16*  Ybf  = (u16*)alloc((size_t)NTOK * 512 * 2);
    u16*  Hbf  = (u16*)alloc((size_t)NTOK * 512 * 2);
    u16*  Astk = (u16*)alloc(1152 * 512 * 2);
    float* bstk = (float*)alloc(1024 * 4);
    float* pb   = (float*)alloc(8 * 4);
    u16*  Aow  = (u16*)alloc(512 * 512 * 2);
    u16*  vnT  = (u16*)alloc(512 * 512 * 2);
    u16*  Wvo  = (u16*)alloc(512 * 512 * 2);
    float* a_en = (float*)alloc(512 * 4);
    float* a_pr = (float*)alloc(512 * 4);
    float* a_rs = (float*)alloc(512 * 4);
    float* b_vo = (float*)alloc(512 * 4);
    float* c_cn = (float*)alloc(512 * 4);
    float* Mss  = (float*)alloc(512 * 8 * 4);
    float* Mcs  = (float*)alloc(512 * 8 * 4);
    float* wp   = (float*)alloc((size_t)NTOK * 8 * 4);
    float* wdotp= (float*)alloc((size_t)NTOK * 4 * 4);
    float* wss  = (float*)alloc((size_t)NTOK * 8 * 4);
    float* wcs  = (float*)alloc((size_t)NTOK * 8 * 4);
    float* wsc  = (float*)alloc((size_t)NTOK * 4 * 4);

    k_fold<<<2176, 256, 0, stream>>>(vnw1, vnnw, vnnb, vnb1, unw1, unnw, unnb, unb1,
                                     sbpw, sbpb, sbnw, sbnb, cbpw, cbpb, cbnw, cbnb,
                                     outw, enw, enb, prw, prb, rsw, rsb, sspw, sspb, cspw, cspb,
                                     vnw2, vnb2,
                                     Astk, bstk, pb, Aow, vnT, a_en, a_pr, a_rs, b_vo, c_cn, Mss, Mcs);
    k_token<<<NTOK / 4, 256, 0, stream>>>(x, Ybf);
    k_gemm1<<<dim3(10, 256), 256, 0, stream>>>(Ybf, Astk, bstk, pb, unw2, Aow, vnT, Wvo,
                                               Hbf, wp, wdotp);
    k_bank<<<NTOK / 256, 256, 0, stream>>>(wp, wdotp, unb2, sbsw, sbsb, cbsw, cbsb,
                                           suplog, confw, drvb, biasres, emlg, emll, emlb, updthr,
                                           wss, wcs, wsc);
    k_gemm2<<<dim3(4, 256), 256, 0, stream>>>(Hbf, Wvo, wsc, wss, wcs, a_en, a_pr, a_rs, b_vo, c_cn,
                                              Mss, Mcs, outb, out);
}

// Round 11
// 152.974 us; speedup vs baseline: 1.7740x; 1.7740x over previous
//
#include <hip/hip_runtime.h>
#include <stdint.h>

typedef unsigned short u16;
typedef __bf16 bf16x8 __attribute__((ext_vector_type(8)));
typedef float f32x4 __attribute__((ext_vector_type(4)));
typedef __attribute__((address_space(1))) void gvoid;
typedef __attribute__((address_space(3))) void lvoid;

#define NTOK 32768

#define FENCE() asm volatile("" ::: "memory")
#define SBAR()  do { FENCE(); __builtin_amdgcn_s_barrier(); FENCE(); } while (0)
#define SVM4()  asm volatile("s_waitcnt vmcnt(4)" ::: "memory")
#define SVM0()  asm volatile("s_waitcnt vmcnt(0)" ::: "memory")

__device__ __forceinline__ u16 f2bf(float f) {
    unsigned u = __float_as_uint(f);
    u += 0x7fffu + ((u >> 16) & 1u);
    return (u16)(u >> 16);
}
__device__ __forceinline__ float softplusf(float x) {
    return fmaxf(x, 0.f) + log1pf(expf(-fabsf(x)));
}
__device__ __forceinline__ float geluf(float x) {
    return 0.5f * x * (1.f + erff(x * 0.7071067811865475f));
}
__device__ __forceinline__ float wave_sum(float v) {
#pragma unroll
    for (int o = 32; o > 0; o >>= 1) v += __shfl_xor(v, o);
    return v;
}
__device__ __forceinline__ float blk_sum(float v) {
    __shared__ float sm[4];
    v = wave_sum(v);
    __syncthreads();
    if ((threadIdx.x & 63) == 0) sm[threadIdx.x >> 6] = v;
    __syncthreads();
    return sm[0] + sm[1] + sm[2] + sm[3];
}

// ---------------------------------------------------------------- fold / precompute
// Astk rows: [0,512) vn folded, [512,1024) un folded, [1024,1032) bank-proj folded, [1032,1152) zero
__global__ void k_fold(
    const float* __restrict__ vnw1, const float* __restrict__ vnnw, const float* __restrict__ vnnb, const float* __restrict__ vnb1,
    const float* __restrict__ unw1, const float* __restrict__ unnw, const float* __restrict__ unnb, const float* __restrict__ unb1,
    const float* __restrict__ sbpw, const float* __restrict__ sbpb, const float* __restrict__ sbnw, const float* __restrict__ sbnb,
    const float* __restrict__ cbpw, const float* __restrict__ cbpb, const float* __restrict__ cbnw, const float* __restrict__ cbnb,
    const float* __restrict__ outw, const float* __restrict__ enw, const float* __restrict__ enb,
    const float* __restrict__ prw, const float* __restrict__ prb,
    const float* __restrict__ rsw, const float* __restrict__ rsb,
    const float* __restrict__ sspw, const float* __restrict__ sspb,
    const float* __restrict__ cspw, const float* __restrict__ cspb,
    const float* __restrict__ vnw2, const float* __restrict__ vnb2,
    u16* __restrict__ Astk, float* __restrict__ bstk, float* __restrict__ pb,
    u16* __restrict__ Aow, u16* __restrict__ vnT,
    float* __restrict__ a_en, float* __restrict__ a_pr, float* __restrict__ a_rs,
    float* __restrict__ b_vo, float* __restrict__ c_cn, float* __restrict__ Mss, float* __restrict__ Mcs)
{
    const int b = blockIdx.x, t = threadIdx.x;
    if (b < 1024) {
        const float *w1, *nw, *nb; float bias;
        if (b < 512) { w1 = vnw1 + (size_t)b * 512; nw = vnnw; nb = vnnb; bias = vnb1[b]; }
        else { int r = b - 512; w1 = unw1 + (size_t)r * 512; nw = unnw; nb = unnb; bias = unb1[r]; }
        float part = 0.f;
        for (int d = t; d < 512; d += 256) {
            float wv = w1[d];
            Astk[(size_t)b * 512 + d] = f2bf(wv * nw[d]);
            part += wv * nb[d];
        }
        float s = blk_sum(part);
        if (t == 0) bstk[b] = bias + s;
    } else if (b < 1032) {
        int j = b - 1024;
        const float *pw, *nw, *nb; float bias;
        if (j < 4) { pw = sbpw + j * 512; nw = sbnw; nb = sbnb; bias = sbpb[j]; }
        else { pw = cbpw + (j - 4) * 512; nw = cbnw; nb = cbnb; bias = cbpb[j - 4]; }
        float part = 0.f;
        for (int d = t; d < 512; d += 256) {
            float wv = pw[d];
            Astk[(size_t)(1024 + j) * 512 + d] = f2bf(wv * nw[d]);
            part += wv * nb[d];
        }
        float s = blk_sum(part);
        if (t == 0) pb[j] = bias + s;
    } else if (b < 1152) {
        for (int d = t; d < 512; d += 256) Astk[(size_t)b * 512 + d] = 0;
    } else if (b < 1664) {
        int i = b - 1152;
        const float* ow = outw + (size_t)i * 3072;
        float pen = 0, ppr = 0, prs = 0, pbv = 0, pcc = 0;
        float pms[8], pmc[8];
#pragma unroll
        for (int k = 0; k < 8; k++) { pms[k] = 0.f; pmc[k] = 0.f; }
        for (int h = t; h < 512; h += 256) {
            float o0 = ow[h];        Aow[(size_t)i * 512 + h] = f2bf(o0); pbv += o0 * vnb2[h];
            float o1 = ow[512 + h];  pen += o1 * enw[h]; pcc += o1 * enb[h];
            float o2 = ow[1024 + h]; ppr += o2 * prw[h]; pcc += o2 * prb[h];
            float o3 = ow[1536 + h]; prs += o3 * rsw[h]; pcc += o3 * rsb[h];
            float o4 = ow[2048 + h]; pcc += o4 * sspb[h];
            float o5 = ow[2560 + h]; pcc += o5 * cspb[h];
#pragma unroll
            for (int k = 0; k < 8; k++) { pms[k] += o4 * sspw[h * 8 + k]; pmc[k] += o5 * cspw[h * 8 + k]; }
        }
        float r;
        r = blk_sum(pen); if (t == 0) a_en[i] = r;
        r = blk_sum(ppr); if (t == 0) a_pr[i] = r;
        r = blk_sum(prs); if (t == 0) a_rs[i] = r;
        r = blk_sum(pbv); if (t == 0) b_vo[i] = r;
        r = blk_sum(pcc); if (t == 0) c_cn[i] = r;
        for (int k = 0; k < 8; k++) { r = blk_sum(pms[k]); if (t == 0) Mss[i * 8 + k] = r; }
        for (int k = 0; k < 8; k++) { r = blk_sum(pmc[k]); if (t == 0) Mcs[i * 8 + k] = r; }
    } else {
        int hrow = b - 1664;
        for (int o = t; o < 512; o += 256)
            vnT[(size_t)hrow * 512 + o] = f2bf(vnw2[(size_t)o * 512 + hrow]);
    }
}

// ================================================================ 8-phase 128x128 GEMM mainloop, 256 threads
// Proven config (R9: 70.7 µs, VGPR 112, no spill, no scratch traffic). 4 waves
// (wm=w>>1, wn=w&1), wave tile 64x64, acc[4][4]=64 VGPR. LDS 64KB (sA0/sA1/sB0/sB1
// each [128][64] u16). Both-sides XOR swizzle: slot (row,s) holds G[row][s^(row&7)].
__device__ __forceinline__ void load_bfrag8(const u16* bufB, bf16x8 (&bfrag)[4][2], int wn, int l) {
#pragma unroll
    for (int nt = 0; nt < 4; nt++) {
        const int row = wn * 64 + nt * 16 + (l & 15);
#pragma unroll
        for (int ks = 0; ks < 2; ks++) {
            const int s = (ks * 4 + (l >> 4)) ^ (row & 7);
            bfrag[nt][ks] = *(const bf16x8*)(bufB + row * 64 + (s << 3));
        }
    }
}

template <int Q>
__device__ __forceinline__ void load_aquad8(const u16* bufA, bf16x8 (&af)[2], int wm, int l) {
    const int row = wm * 64 + Q * 16 + (l & 15);
#pragma unroll
    for (int ks = 0; ks < 2; ks++) {
        const int s = (ks * 4 + (l >> 4)) ^ (row & 7);
        af[ks] = *(const bf16x8*)(bufA + row * 64 + (s << 3));
    }
}

template <int Q>
__device__ __forceinline__ void do_mfma8(bf16x8 (&af)[2], bf16x8 (&bfrag)[4][2], f32x4 (&acc)[4][4]) {
#pragma unroll
    for (int nt = 0; nt < 4; nt++)
#pragma unroll
        for (int ks = 0; ks < 2; ks++)
            acc[Q][nt] = __builtin_amdgcn_mfma_f32_16x16x32_bf16(af[ks], bfrag[nt][ks], acc[Q][nt], 0, 0, 0);
}

#define PHASE8(Q, bufA_, bufB_, READB, STAGE_STMT, VM_STMT)       \
    do {                                                          \
        if (READB) load_bfrag8(bufB_, bfrag, wn, l);              \
        bf16x8 af[2];                                             \
        load_aquad8<Q>(bufA_, af, wm, l);                         \
        STAGE_STMT;                                               \
        SBAR();                                                   \
        __builtin_amdgcn_s_setprio(1);                            \
        do_mfma8<Q>(af, bfrag, acc);                              \
        __builtin_amdgcn_s_setprio(0);                            \
        VM_STMT;                                                  \
        SBAR();                                                   \
    } while (0)

// K = 512 (8 K-tiles of BK=64). STG(tile) = 4 global_load_lds/thread.
__device__ __forceinline__ void gemm8_mainloop(const u16* __restrict__ Ag, const u16* __restrict__ Bg,
                                               size_t arow0, size_t brow0,
                                               u16* sm, f32x4 (&acc)[4][4], int w, int l)
{
    const int wm = w >> 1, wn = w & 1;
    u16* const sA0 = sm;
    u16* const sA1 = sm + 8192;
    u16* const sB0 = sm + 16384;
    u16* const sB1 = sm + 24576;
    const int rchunk = l >> 3;                       // row within 8-row chunk
    const int gc = (((l & 7) ^ ((l >> 3) & 7)) << 3);// pre-swizzled global col (u16)

    auto STG = [&](const u16* g, size_t rb, int tile, u16* lbase) {
        const int kt = tile * 64;
#pragma unroll
        for (int i = 0; i < 4; i++) {
            const int r0 = (w * 4 + i) * 8;
            __builtin_amdgcn_global_load_lds(
                (gvoid*)const_cast<u16*>(g + (rb + r0 + rchunk) * 512 + kt + gc),
                (lvoid*)(lbase + r0 * 64), 16, 0, 0);
        }
    };

    STG(Ag, arow0, 0, sA0);
    STG(Bg, brow0, 0, sB0);
    STG(Bg, brow0, 1, sB1);
    SVM4();   // t0's A+B landed; B(t1) outstanding
    SBAR();

    bf16x8 bfrag[4][2];
    for (int it = 0; it < 4; ++it) {
        const int t1 = 2 * it + 1, t2 = 2 * it + 2, t3 = 2 * it + 3;
        const bool lastit = (it == 3);
        // phases 1-4: compute tile t0=2it from buf0
        PHASE8(0, sA0, sB0, true,  { STG(Ag, arow0, t1, sA1); }, );
        PHASE8(1, sA0, sB0, false, { if (t2 < 8) STG(Bg, brow0, t2, sB0); }, );
        PHASE8(2, sA0, sB0, false, { }, );
        PHASE8(3, sA0, sB0, false, { }, { if (lastit) { SVM0(); } else { SVM4(); } });
        // phases 5-8: compute tile t1 from buf1
        PHASE8(0, sA1, sB1, true,  { if (t2 < 8) STG(Ag, arow0, t2, sA0); }, );
        PHASE8(1, sA1, sB1, false, { if (t3 < 8) STG(Bg, brow0, t3, sB1); }, );
        PHASE8(2, sA1, sB1, false, { }, );
        PHASE8(3, sA1, sB1, false, { }, { SVM4(); });
    }
}

// ---------------------------------------------------------------- per-token standardize (memory-bound)
__global__ void k_token(const float* __restrict__ x, u16* __restrict__ Ybf)
{
    const int w = threadIdx.x >> 6, l = threadIdx.x & 63;
    const int n = blockIdx.x * 4 + w;
    const float* xr = x + (size_t)n * 512;
    float4 xa = *(const float4*)(xr + 4 * l);
    float4 xb = *(const float4*)(xr + 256 + 4 * l);
    float v[8] = {xa.x, xa.y, xa.z, xa.w, xb.x, xb.y, xb.z, xb.w};
    float s1 = 0.f, s2 = 0.f;
#pragma unroll
    for (int c = 0; c < 8; c++) { s1 += v[c]; s2 += v[c] * v[c]; }
    s1 = wave_sum(s1); s2 = wave_sum(s2);
    const float mean = s1 * (1.f / 512.f);
    const float var = s2 * (1.f / 512.f) - mean * mean;
    const float rstd = rsqrtf(var + 1e-5f);
    float y[8];
#pragma unroll
    for (int c = 0; c < 8; c++) y[c] = (v[c] - mean) * rstd;
    *(ushort4*)(Ybf + (size_t)n * 512 + 4 * l) = make_ushort4(f2bf(y[0]), f2bf(y[1]), f2bf(y[2]), f2bf(y[3]));
    *(ushort4*)(Ybf + (size_t)n * 512 + 256 + 4 * l) = make_ushort4(f2bf(y[4]), f2bf(y[5]), f2bf(y[6]), f2bf(y[7]));
}

// ---------------------------------------------------------------- GEMM1: bx 0-3 H, 4-7 un dot, 8 bank proj, 9 Wvo (16 tiles)
__global__ __launch_bounds__(256, 2) void k_gemm1(const u16* __restrict__ Y, const u16* __restrict__ Ast,
                                                  const float* __restrict__ bstk, const float* __restrict__ pb,
                                                  const float* __restrict__ unw2,
                                                  const u16* __restrict__ Aow, const u16* __restrict__ vnT,
                                                  u16* __restrict__ Wvo,
                                                  u16* __restrict__ H, float* __restrict__ wp,
                                                  float* __restrict__ wdotp)
{
    __shared__ __align__(16) u16 smem[32768];
    const f32x4 zero = {0.f, 0.f, 0.f, 0.f};
    f32x4 acc[4][4];
#pragma unroll
    for (int a = 0; a < 4; a++)
#pragma unroll
        for (int c = 0; c < 4; c++) acc[a][c] = zero;
    // XCD-aware bijective swizzle (nwg = 10*256 = 2560, %8==0)
    const int nwg = gridDim.x * gridDim.y;
    const int lin = blockIdx.y * gridDim.x + blockIdx.x;
    const int swz = (lin & 7) * (nwg >> 3) + (lin >> 3);
    const int by = swz / gridDim.x, bx = swz % gridDim.x;
    const int t = threadIdx.x, w = t >> 6, l = t & 63;
    const int wr = ((w >> 1) << 6), wc = ((w & 1) << 6);
    const int lr = ((l >> 4) << 2), lc = l & 15;

    if (bx == 9) {
        // Wvo = Aow @ vnT^T (512x512x512) folded in as 16 tiles; other blocks exit
        if (by >= 16) return;
        gemm8_mainloop(Aow, vnT, (size_t)(by >> 2) * 128, (size_t)(by & 3) * 128, smem, acc, w, l);
        const int rbase = (by >> 2) * 128 + wr;
        const int cbase = (by & 3) * 128 + wc;
#pragma unroll
        for (int rt = 0; rt < 4; rt++)
#pragma unroll
            for (int ct = 0; ct < 4; ct++)
#pragma unroll
                for (int j = 0; j < 4; j++)
                    Wvo[(size_t)(rbase + rt * 16 + lr + j) * 512 + cbase + ct * 16 + lc] = f2bf(acc[rt][ct][j]);
        return;
    }

    gemm8_mainloop(Y, Ast, (size_t)by * 128, (size_t)bx * 128, smem, acc, w, l);

    if (bx == 8) {
        // bank projections: only cols 1024..1031 real ((w&1)==0, ct=0, lc<8)
        if ((w & 1) == 0 && lc < 8) {
            const float bv = pb[lc];
            const int rbase = by * 128 + wr;
#pragma unroll
            for (int rt = 0; rt < 4; rt++)
#pragma unroll
                for (int j = 0; j < 4; j++) {
                    const int n = rbase + rt * 16 + lr + j;
                    wp[(size_t)n * 8 + lc] = acc[rt][0][j] + bv;
                }
        }
        return;
    }
    if (bx >= 4) {
        // uncertainty half: dot( gelu(u_h), un_w2 ) partials; H never materialized
        const int cb = (bx - 4) * 128;
        float part[4][4];
#pragma unroll
        for (int rt = 0; rt < 4; rt++)
#pragma unroll
            for (int j = 0; j < 4; j++) part[rt][j] = 0.f;
#pragma unroll
        for (int ct = 0; ct < 4; ct++) {
            const int col = cb + wc + ct * 16 + lc;
            const float bv = bstk[512 + col];
            const float w2 = unw2[col];
#pragma unroll
            for (int rt = 0; rt < 4; rt++)
#pragma unroll
                for (int j = 0; j < 4; j++)
                    part[rt][j] += geluf(acc[rt][ct][j] + bv) * w2;
        }
        float* sf = (float*)smem;   // 128 rows x 32 slots = 16 KB
        const int slot = ((w & 1) << 4) | lc;
        __syncthreads();
#pragma unroll
        for (int rt = 0; rt < 4; rt++)
#pragma unroll
            for (int j = 0; j < 4; j++)
                sf[(wr + rt * 16 + lr + j) * 32 + slot] = part[rt][j];
        __syncthreads();
        if (t < 128) {
            float s = 0.f;
#pragma unroll
            for (int k2 = 0; k2 < 32; k2++) s += sf[t * 32 + k2];
            wdotp[(size_t)(bx - 4) * NTOK + by * 128 + t] = s;
        }
        return;
    }
    // v-half: gelu + bias, stage C-tile in LDS [128][136] u16, coalesced 256B-row writes
    __syncthreads();
#pragma unroll
    for (int ct = 0; ct < 4; ct++) {
        const int col = wc + ct * 16 + lc;
        const float bv = bstk[bx * 128 + col];
#pragma unroll
        for (int rt = 0; rt < 4; rt++) {
            const int row = wr + rt * 16 + lr;
#pragma unroll
            for (int j = 0; j < 4; j++)
                smem[(row + j) * 136 + col] = f2bf(geluf(acc[rt][ct][j] + bv));
        }
    }
    __syncthreads();
    const size_t gbase = (size_t)(by * 128) * 512 + bx * 128;
#pragma unroll
    for (int jj = 0; jj < 8; jj++) {
        const int r = jj * 16 + (t >> 4), u = t & 15;
        bf16x8 vv = *(const bf16x8*)(smem + r * 136 + u * 8);
        *(bf16x8*)(H + gbase + (size_t)r * 512 + u * 8) = vv;
    }
}

// ---------------------------------------------------------------- GEMM2: value path + fused bank/EML + MERC epilogue
// Bank scalar math fused into the prologue: threads 0..127 each compute one token's
// {act,energy,precision,resistance,ss[8],cs[8]} into LDS (10 KB) — replaces the k_bank
// dispatch and the wsc/wss/wcs global round-trips. 4x redundant across bx (trivial VALU).
__global__ __launch_bounds__(256, 2) void k_gemm2(const u16* __restrict__ H, const u16* __restrict__ Wvo,
    const float* __restrict__ wp, const float* __restrict__ wdotp,
    const float* __restrict__ unb2,
    const float* __restrict__ sbsw, const float* __restrict__ sbsb,
    const float* __restrict__ cbsw, const float* __restrict__ cbsb,
    const float* __restrict__ suplog, const float* __restrict__ confw,
    const float* __restrict__ drvb, const float* __restrict__ biasres,
    const float* __restrict__ emlg, const float* __restrict__ emll,
    const float* __restrict__ emlb, const float* __restrict__ updthr,
    const float* __restrict__ a_en, const float* __restrict__ a_pr, const float* __restrict__ a_rs,
    const float* __restrict__ b_vo, const float* __restrict__ c_cn,
    const float* __restrict__ Mss, const float* __restrict__ Mcs,
    const float* __restrict__ outb, float* __restrict__ out)
{
    __shared__ __align__(16) u16 smem[32768];
    __shared__ float sbank[128 * 20];   // per-token: 0 act, 1 eng, 2 prc, 3 res, 4..11 ss, 12..19 cs
    const f32x4 zero = {0.f, 0.f, 0.f, 0.f};
    f32x4 acc[4][4];
#pragma unroll
    for (int a = 0; a < 4; a++)
#pragma unroll
        for (int c = 0; c < 4; c++) acc[a][c] = zero;
    // XCD-aware bijective swizzle (nwg = 4*256 = 1024, %8==0)
    const int nwg = gridDim.x * gridDim.y;
    const int lin = blockIdx.y * gridDim.x + blockIdx.x;
    const int swz = (lin & 7) * (nwg >> 3) + (lin >> 3);
    const int by = swz / gridDim.x, bx = swz % gridDim.x;
    const int t = threadIdx.x, w = t >> 6, l = t & 63;

    if (t < 128) {
        const int n = by * 128 + t;
        float4 p0 = *(const float4*)(wp + (size_t)n * 8);
        float4 p1 = *(const float4*)(wp + (size_t)n * 8 + 4);
        float p[8] = {p0.x, p0.y, p0.z, p0.w, p1.x, p1.y, p1.z, p1.w};
        const float dot = wdotp[n] + wdotp[NTOK + n] + wdotp[2 * NTOK + n] + wdotp[3 * NTOK + n];
        float sf[4], lsv[4], cf[4];
#pragma unroll
        for (int j = 0; j < 4; j++) {
            sf[j] = softplusf(p[j]) + 1e-4f;
            lsv[j] = logf(sf[j]);
            cf[j] = softplusf(p[j + 4]);
        }
        const float smn = 0.25f * (sf[0] + sf[1] + sf[2] + sf[3]);
        float sd = 0.f;
#pragma unroll
        for (int j = 0; j < 4; j++) sd += (sf[j] - smn) * (sf[j] - smn);
        const float sstd = sqrtf(0.25f * sd);
        const float lmn = 0.25f * (lsv[0] + lsv[1] + lsv[2] + lsv[3]);
        const float lmx = fmaxf(fmaxf(lsv[0], lsv[1]), fmaxf(lsv[2], lsv[3]));
        const float cmn = 0.25f * (cf[0] + cf[1] + cf[2] + cf[3]);
        float cd = 0.f;
#pragma unroll
        for (int j = 0; j < 4; j++) cd += (cf[j] - cmn) * (cf[j] - cmn);
        const float cstd = sqrtf(0.25f * cd);
        const float cmx = fmaxf(fmaxf(cf[0], cf[1]), fmaxf(cf[2], cf[3]));
        const float cmi = fminf(fminf(cf[0], cf[1]), fminf(cf[2], cf[3]));
        float seed_s[4] = {smn, sstd, lmn, lmx};
        float seed_c[4] = {cmn, cstd, cmx, cmi};
#pragma unroll
        for (int k = 0; k < 8; k++) {
            float a = sbsb[k], b2 = cbsb[k];
#pragma unroll
            for (int j = 0; j < 4; j++) { a += sbsw[k * 4 + j] * seed_s[j]; b2 += cbsw[k * 4 + j] * seed_c[j]; }
            sbank[t * 20 + 4 + k] = a;
            sbank[t * 20 + 12 + k] = b2;
        }
        float mx = fmaxf(fmaxf(suplog[0], suplog[1]), fmaxf(suplog[2], suplog[3]));
        float e[4], se = 0.f;
#pragma unroll
        for (int j = 0; j < 4; j++) { e[j] = expf(suplog[j] - mx); se += e[j]; }
        float dv = 0.f, wcv = 0.f;
#pragma unroll
        for (int j = 0; j < 4; j++) { dv += lsv[j] * (e[j] / se); wcv += cf[j] * softplusf(confw[j]); }
        const float drive = drvb[0] + 0.5f * dv;
        const float unc = softplusf(dot + unb2[0]);
        const float res = biasres[0] + 0.5f * wcv + unc;
        const float er = emlg[0] * drive - emll[0] * res + emlb[0];
        const float energy = 3.f * tanhf(er * (1.f / 3.f));
        sbank[t * 20 + 0] = 1.f / (1.f + expf(-energy));
        sbank[t * 20 + 1] = energy;
        sbank[t * 20 + 2] = softplusf(energy - updthr[0]);
        sbank[t * 20 + 3] = res;
    }
    __syncthreads();

    gemm8_mainloop(H, Wvo, (size_t)by * 128, (size_t)bx * 128, smem, acc, w, l);

    const int rl0 = ((w >> 1) << 6);
    const int cbase = bx * 128 + ((w & 1) << 6);
    const int lr = ((l >> 4) << 2), lc = l & 15;
    float bvo4[4], aen4[4], apr4[4], ars4[4], cc4[4], ms4[4][8], mc4[4][8];
#pragma unroll
    for (int ct = 0; ct < 4; ct++) {
        const int i = cbase + ct * 16 + lc;
        bvo4[ct] = b_vo[i]; aen4[ct] = a_en[i]; apr4[ct] = a_pr[i]; ars4[ct] = a_rs[i];
        cc4[ct] = c_cn[i] + outb[i];
#pragma unroll
        for (int k = 0; k < 8; k++) { ms4[ct][k] = Mss[i * 8 + k]; mc4[ct][k] = Mcs[i * 8 + k]; }
    }
#pragma unroll
    for (int rt = 0; rt < 4; rt++)
#pragma unroll
        for (int j = 0; j < 4; j++) {
            const int nl = rl0 + rt * 16 + lr + j;          // token index within block (0..127)
            const size_t n = (size_t)by * 128 + nl;
            const float act = sbank[nl * 20 + 0];
            const float eng = sbank[nl * 20 + 1];
            const float prc = sbank[nl * 20 + 2];
            const float res = sbank[nl * 20 + 3];
#pragma unroll
            for (int ct = 0; ct < 4; ct++) {
                const int i = cbase + ct * 16 + lc;
                float o = act * (acc[rt][ct][j] + bvo4[ct]) + eng * aen4[ct] + prc * apr4[ct]
                        + res * ars4[ct] + cc4[ct];
#pragma unroll
                for (int k = 0; k < 8; k++)
                    o += ms4[ct][k] * sbank[nl * 20 + 4 + k] + mc4[ct][k] * sbank[nl * 20 + 12 + k];
                out[n * 512 + i] = o;
            }
        }
}

// ---------------------------------------------------------------- host
extern "C" void kernel_launch(void* const* d_in, const int* in_sizes, int n_in,
                              void* d_out, int out_size, void* d_ws, size_t ws_size,
                              hipStream_t stream)
{
    const float* x       = (const float*)d_in[0];
    const float* sbnw    = (const float*)d_in[1];
    const float* sbnb    = (const float*)d_in[2];
    const float* sbpw    = (const float*)d_in[3];
    const float* sbpb    = (const float*)d_in[4];
    const float* sbsw    = (const float*)d_in[5];
    const float* sbsb    = (const float*)d_in[6];
    const float* cbnw    = (const float*)d_in[7];
    const float* cbnb    = (const float*)d_in[8];
    const float* cbpw    = (const float*)d_in[9];
    const float* cbpb    = (const float*)d_in[10];
    const float* cbsw    = (const float*)d_in[11];
    const float* cbsb    = (const float*)d_in[12];
    const float* vnnw    = (const float*)d_in[13];
    const float* vnnb    = (const float*)d_in[14];
    const float* vnw1    = (const float*)d_in[15];
    const float* vnb1    = (const float*)d_in[16];
    const float* vnw2    = (const float*)d_in[17];
    const float* vnb2    = (const float*)d_in[18];
    const float* unnw    = (const float*)d_in[19];
    const float* unnb    = (const float*)d_in[20];
    const float* unw1    = (const float*)d_in[21];
    const float* unb1    = (const float*)d_in[22];
    const float* unw2    = (const float*)d_in[23];
    const float* unb2    = (const float*)d_in[24];
    const float* enw     = (const float*)d_in[25];
    const float* enb     = (const float*)d_in[26];
    const float* prw     = (const float*)d_in[27];
    const float* prb     = (const float*)d_in[28];
    const float* rsw     = (const float*)d_in[29];
    const float* rsb     = (const float*)d_in[30];
    const float* sspw    = (const float*)d_in[31];
    const float* sspb    = (const float*)d_in[32];
    const float* cspw    = (const float*)d_in[33];
    const float* cspb    = (const float*)d_in[34];
    const float* outw    = (const float*)d_in[35];
    const float* outb    = (const float*)d_in[36];
    const float* suplog  = (const float*)d_in[37];
    const float* confw   = (const float*)d_in[38];
    const float* drvb    = (const float*)d_in[39];
    const float* biasres = (const float*)d_in[40];
    const float* updthr  = (const float*)d_in[41];
    const float* emlg    = (const float*)d_in[42];
    const float* emll    = (const float*)d_in[43];
    const float* emlb    = (const float*)d_in[44];
    float* out = (float*)d_out;
    (void)in_sizes; (void)n_in; (void)out_size; (void)ws_size;

    char* wsp = (char*)d_ws;
    size_t off = 0;
    auto alloc = [&](size_t bytes) { char* p = wsp + off; off = (off + bytes + 255) & ~(size_t)255; return p; };
    u16*  Ybf  = (u16*)alloc((size_t)NTOK * 512 * 2);
    u16*  Hbf  = (u16*)alloc((size_t)NTOK * 512 * 2);
    u16*  Astk = (u16*)alloc(1152 * 512 * 2);
    float* bstk = (float*)alloc(1024 * 4);
    float* pb   = (float*)alloc(8 * 4);
    u16*  Aow  = (u16*)alloc(512 * 512 * 2);
    u16*  vnT  = (u16*)alloc(512 * 512 * 2);
    u16*  Wvo  = (u16*)alloc(512 * 512 * 2);
    float* a_en = (float*)alloc(512 * 4);
    float* a_pr = (float*)alloc(512 * 4);
    float* a_rs = (float*)alloc(512 * 4);
    float* b_vo = (float*)alloc(512 * 4);
    float* c_cn = (float*)alloc(512 * 4);
    float* Mss  = (float*)alloc(512 * 8 * 4);
    float* Mcs  = (float*)alloc(512 * 8 * 4);
    float* wp   = (float*)alloc((size_t)NTOK * 8 * 4);
    float* wdotp= (float*)alloc((size_t)NTOK * 4 * 4);

    k_fold<<<2176, 256, 0, stream>>>(vnw1, vnnw, vnnb, vnb1, unw1, unnw, unnb, unb1,
                                     sbpw, sbpb, sbnw, sbnb, cbpw, cbpb, cbnw, cbnb,
                                     outw, enw, enb, prw, prb, rsw, rsb, sspw, sspb, cspw, cspb,
                                     vnw2, vnb2,
                                     Astk, bstk, pb, Aow, vnT, a_en, a_pr, a_rs, b_vo, c_cn, Mss, Mcs);
    k_token<<<NTOK / 4, 256, 0, stream>>>(x, Ybf);
    k_gemm1<<<dim3(10, 256), 256, 0, stream>>>(Ybf, Astk, bstk, pb, unw2, Aow, vnT, Wvo,
                                               Hbf, wp, wdotp);
    k_gemm2<<<dim3(4, 256), 256, 0, stream>>>(Hbf, Wvo, wp, wdotp, unb2, sbsw, sbsb, cbsw, cbsb,
                                              suplog, confw, drvb, biasres, emlg, emll, emlb, updthr,
                                              a_en, a_pr, a_rs, b_vo, c_cn, Mss, Mcs, outb, out);
}